// Round 1
// baseline (808.342 us; speedup 1.0000x reference)
//
#include <hip/hip_runtime.h>
#include <stdint.h>

// Voxelization: per scale in {2,4,8,1}:
//   full_coors [N,4] int32 (b,x,y,z) ; coors_inv [N] int32 ; coors [M,4] int32 (b,z,y,x)
// Strategy: bitmap over bounded key space + popcount prefix sum == sorted unique.
// Chunk offsets into d_out are data-dependent (M per scale), kept in devOff[] on device.

#define CHUNK 4096  // bitmap words per scan block (256 thr x 16 words)

__global__ void k_init(long long* devOff) {
  if (threadIdx.x == 0) devOff[0] = 0;
}

__global__ __launch_bounds__(256) void k_mark(
    const float* __restrict__ pts, const int* __restrict__ bidx, int n, int scaleIdx,
    float dx, float dy, float dz,          // (float)dims
    float lox, float loy, float loz,       // f32(lo)
    float rx, float ry, float rz,          // f32(hi-lo)
    int sx, int sy, int sz,
    const long long* __restrict__ devOff,
    int* __restrict__ out, uint32_t* __restrict__ keys, uint32_t* __restrict__ bitmap) {
  int j = blockIdx.x * blockDim.x + threadIdx.x;
  if (j >= n) return;
  long long base = devOff[scaleIdx];
  float px = pts[3 * j + 0];
  float py = pts[3 * j + 1];
  float pz = pts[3 * j + 2];
  int b = bidx[j];
  // exact reference arithmetic: trunc( dims * (p - lo) / (hi - lo) ) in f32
  int xi = (int)((dx * (px - lox)) / rx);
  int yi = (int)((dy * (py - loy)) / ry);
  int zi = (int)((dz * (pz - loz)) / rz);
  uint32_t key = (uint32_t)(((b * sx + xi) * sy + yi) * sz + zi);
  keys[j] = key;
  atomicOr(&bitmap[key >> 5], 1u << (key & 31));
  *(int4*)(out + base + (long long)j * 4) = make_int4(b, xi, yi, zi);
}

__global__ __launch_bounds__(256) void k_sumA(
    const uint32_t* __restrict__ bitmap, int nwords, uint32_t* __restrict__ blockSums) {
  __shared__ uint32_t sh[256];
  int t = threadIdx.x;
  int w0 = blockIdx.x * CHUNK + t * 16;
  uint32_t s = 0;
#pragma unroll
  for (int k = 0; k < 16; k++) {
    int w = w0 + k;
    if (w < nwords) s += __popc(bitmap[w]);
  }
  sh[t] = s;
  __syncthreads();
  for (int off = 128; off > 0; off >>= 1) {
    if (t < off) sh[t] += sh[t + off];
    __syncthreads();
  }
  if (t == 0) blockSums[blockIdx.x] = sh[0];
}

// Exclusive-scan blockSums in place (nblocks <= 2048), update devOff[scaleIdx+1].
__global__ __launch_bounds__(256) void k_scanB(
    uint32_t* blockSums, int nblocks, long long* devOff, int scaleIdx, long long fiveN) {
  __shared__ uint32_t sh[256];
  int t = threadIdx.x;
  uint32_t v[8];
  uint32_t s = 0;
#pragma unroll
  for (int k = 0; k < 8; k++) {
    int idx = t * 8 + k;
    uint32_t x = (idx < nblocks) ? blockSums[idx] : 0u;
    v[k] = x;
    s += x;
  }
  sh[t] = s;
  __syncthreads();
  for (int off = 1; off < 256; off <<= 1) {
    uint32_t add = (t >= off) ? sh[t - off] : 0u;
    __syncthreads();
    sh[t] += add;
    __syncthreads();
  }
  uint32_t run = sh[t] - s;  // exclusive base for this thread
#pragma unroll
  for (int k = 0; k < 8; k++) {
    int idx = t * 8 + k;
    if (idx < nblocks) blockSums[idx] = run;
    run += v[k];
  }
  if (t == 0) {
    uint32_t total = sh[255];
    devOff[scaleIdx + 1] = devOff[scaleIdx] + fiveN + 4LL * (long long)total;
  }
}

__global__ __launch_bounds__(256) void k_prefC(
    const uint32_t* __restrict__ bitmap, int nwords,
    const uint32_t* __restrict__ blockSums, uint32_t* __restrict__ prefix) {
  __shared__ uint32_t sh[256];
  int t = threadIdx.x;
  int w0 = blockIdx.x * CHUNK + t * 16;
  uint32_t words[16];
  uint32_t s = 0;
#pragma unroll
  for (int k = 0; k < 16; k++) {
    int w = w0 + k;
    uint32_t wd = (w < nwords) ? bitmap[w] : 0u;
    words[k] = wd;
    s += __popc(wd);
  }
  sh[t] = s;
  __syncthreads();
  for (int off = 1; off < 256; off <<= 1) {
    uint32_t add = (t >= off) ? sh[t - off] : 0u;
    __syncthreads();
    sh[t] += add;
    __syncthreads();
  }
  uint32_t run = blockSums[blockIdx.x] + (sh[t] - s);
#pragma unroll
  for (int k = 0; k < 16; k++) {
    int w = w0 + k;
    if (w < nwords) prefix[w] = run;
    run += __popc(words[k]);
  }
}

__global__ __launch_bounds__(256) void k_inv(
    const uint32_t* __restrict__ keys, int n,
    const uint32_t* __restrict__ bitmap, const uint32_t* __restrict__ prefix,
    const long long* __restrict__ devOff, int scaleIdx, long long fourN,
    int* __restrict__ out) {
  int j = blockIdx.x * blockDim.x + threadIdx.x;
  if (j >= n) return;
  uint32_t key = keys[j];
  uint32_t w = key >> 5;
  uint32_t bit = key & 31u;
  uint32_t inv = prefix[w] + __popc(bitmap[w] & ((1u << bit) - 1u));
  out[devOff[scaleIdx] + fourN + j] = (int)inv;
}

__global__ __launch_bounds__(256) void k_uniq(
    const uint32_t* __restrict__ bitmap, int nwords,
    const uint32_t* __restrict__ prefix,
    const long long* __restrict__ devOff, int scaleIdx, long long fiveN,
    int lz, int lyz, int lxyz, int mz, int my, int mx, int* __restrict__ out) {
  int w = blockIdx.x * blockDim.x + threadIdx.x;
  if (w >= nwords) return;
  uint32_t wd = bitmap[w];
  if (!wd) return;
  uint32_t pos = prefix[w];
  long long base = devOff[scaleIdx] + fiveN;
  while (wd) {
    int bit = __ffs(wd) - 1;
    wd &= wd - 1u;
    uint32_t key = ((uint32_t)w << 5) + (uint32_t)bit;
    int z = (int)(key & (uint32_t)mz);
    int y = (int)((key >> lz) & (uint32_t)my);
    int x = (int)((key >> lyz) & (uint32_t)mx);
    int b = (int)(key >> lxyz);
    *(int4*)(out + base + (long long)pos * 4) = make_int4(b, z, y, x);
    pos++;
  }
}

extern "C" void kernel_launch(void* const* d_in, const int* in_sizes, int n_in,
                              void* d_out, int out_size, void* d_ws, size_t ws_size,
                              hipStream_t stream) {
  const float* pts = (const float*)d_in[0];
  const int* bidx = (const int*)d_in[1];
  int n = in_sizes[0] / 3;
  int* out = (int*)d_out;

  // ws layout
  char* ws = (char*)d_ws;
  long long* devOff = (long long*)ws;                        // 16 * 8 B
  uint32_t* blockSums = (uint32_t*)(ws + 256);               // 2048 * 4 B
  const long long MAXWORDS = 4195584;                        // scale-1 bitmap words, padded
  uint32_t* bitmap = (uint32_t*)(ws + 16384);
  uint32_t* prefix = (uint32_t*)(ws + 16384 + MAXWORDS * 4);
  uint32_t* keys = (uint32_t*)(ws + 16384 + 2 * MAXWORDS * 4);

  const int scales[4] = {2, 4, 8, 1};
  const long long fourN = 4LL * n, fiveN = 5LL * n;
  const int gridN = (n + 255) / 256;

  hipLaunchKernelGGL(k_init, dim3(1), dim3(1), 0, stream, devOff);

  for (int i = 0; i < 4; i++) {
    int sc = scales[i];
    int sx = (512 + sc - 1) / sc;
    int sy = (512 + sc - 1) / sc;
    int sz = (64 + sc - 1) / sc;
    // bitmap size: cover idx==dims rounding edge (key up to 8*sx*sy*sz + sy*sz + sz)
    long long nbits = 8LL * sx * sy * sz + (long long)sy * sz + sz + 2;
    int nwords = (int)((nbits + 31) / 32);
    int nblocks = (nwords + CHUNK - 1) / CHUNK;  // <= 1025

    int lz = __builtin_ctz((unsigned)sz);
    int ly = __builtin_ctz((unsigned)sy);
    int lx = __builtin_ctz((unsigned)sx);
    int lyz = lz + ly, lxyz = lz + ly + lx;

    hipMemsetAsync(bitmap, 0, (size_t)nwords * 4, stream);

    hipLaunchKernelGGL(k_mark, dim3(gridN), dim3(256), 0, stream,
                       pts, bidx, n, i,
                       (float)sx, (float)sy, (float)sz,
                       -51.2f, -51.2f, -4.0f,
                       102.4f, 102.4f, 6.4f,
                       sx, sy, sz, devOff, out, keys, bitmap);

    hipLaunchKernelGGL(k_sumA, dim3(nblocks), dim3(256), 0, stream, bitmap, nwords, blockSums);
    hipLaunchKernelGGL(k_scanB, dim3(1), dim3(256), 0, stream, blockSums, nblocks, devOff, i, fiveN);
    hipLaunchKernelGGL(k_prefC, dim3(nblocks), dim3(256), 0, stream, bitmap, nwords, blockSums, prefix);
    hipLaunchKernelGGL(k_inv, dim3(gridN), dim3(256), 0, stream,
                       keys, n, bitmap, prefix, devOff, i, fourN, out);
    hipLaunchKernelGGL(k_uniq, dim3((nwords + 255) / 256), dim3(256), 0, stream,
                       bitmap, nwords, prefix, devOff, i, fiveN,
                       lz, lyz, lxyz, sz - 1, sy - 1, sx - 1, out);
  }
}